// Round 1
// baseline (1045.818 us; speedup 1.0000x reference)
//
#include <hip/hip_runtime.h>

#define BATCH 8
#define MAXPOS 2048
#define SEQ 2046
#define NH 12
#define HD 64
#define RLEN 4096   // R[x] = exp(w[|x-2047|]-off), x in [0,4094]; zero-padded tails
#define TT 64       // t-chunk staged in LDS
#define TN 64       // n-tile per block

// ---------------------------------------------------------------------------
// pbv[b, 1+n, h, d] = sum_t exp(w[h,|n-t|]-off[h]) * v[b, 1+t, h, d]
// One block per (n-tile, h, b). R (symmetric kernel) built once per block.
// Thread map: tp = tid&31 -> d0 = 2*tp (float2 of d); nl = tid>>5 in [0,8);
// each thread owns n = n0 + nl + 8*i for i in [0,8).
// ---------------------------------------------------------------------------
__global__ __launch_bounds__(256)
void pbv_kernel(const float* __restrict__ v, const float* __restrict__ w,
                const float* __restrict__ off, float* __restrict__ out) {
    __shared__ float R[RLEN];
    __shared__ float Vs[TT][HD];

    const int tile = blockIdx.x;
    const int h    = blockIdx.y;
    const int b    = blockIdx.z;
    const int n0   = tile * TN;
    const int tid  = threadIdx.x;

    const float offh = off[h];
    const float* wh  = w + h * SEQ;
    for (int x = tid; x < RLEN; x += 256) {
        int k = x - 2047; k = (k < 0) ? -k : k;
        R[x] = (k < SEQ) ? __expf(wh[k] - offh) : 0.f;
    }
    // first __syncthreads() below (top of t0 loop) publishes R before any read

    const int tp = tid & 31;
    const int nl = tid >> 5;
    const int d0 = tp * 2;

    float accx[8], accy[8];
    int   nbase[8];
#pragma unroll
    for (int i = 0; i < 8; ++i) { accx[i] = 0.f; accy[i] = 0.f; nbase[i] = n0 + nl + 8 * i; }

    const float* vb = v + (((size_t)b * MAXPOS + 1) * NH + h) * HD;

    for (int t0 = 0; t0 < SEQ; t0 += TT) {
        __syncthreads();
        // stage V[t0..t0+63][0..63] -> Vs (zero rows past SEQ)
#pragma unroll
        for (int j = 0; j < 4; ++j) {
            int q  = tid + 256 * j;
            int tr = q >> 4;
            int c4 = (q & 15) * 4;
            int t  = t0 + tr;
            float4 val = make_float4(0.f, 0.f, 0.f, 0.f);
            if (t < SEQ) val = *(const float4*)(vb + (size_t)t * (NH * HD) + c4);
            *(float4*)&Vs[tr][c4] = val;
        }
        __syncthreads();

#pragma unroll 4
        for (int tr = 0; tr < TT; ++tr) {
            float2 vv = *(const float2*)&Vs[tr][d0];
#pragma unroll
            for (int i = 0; i < 8; ++i) {
                float e = R[2047 + nbase[i] - t0 - tr];   // broadcast read
                accx[i] += e * vv.x;
                accy[i] += e * vv.y;
            }
        }
    }

    float* ob = out + (((size_t)b * MAXPOS + 1) * NH + h) * HD;
#pragma unroll
    for (int i = 0; i < 8; ++i) {
        int n = nbase[i];
        if (n < SEQ) {
            float2 r; r.x = accx[i]; r.y = accy[i];
            *(float2*)(ob + (size_t)n * (NH * HD) + d0) = r;
        }
    }
}

// ---------------------------------------------------------------------------
// z_pb[1+n, h] = sum_t exp(w[h,|n-t|]-off[h]); tiny vs pbv (0.2% of FLOPs)
// ---------------------------------------------------------------------------
__global__ __launch_bounds__(256)
void zpb_kernel(const float* __restrict__ w, const float* __restrict__ off,
                float* __restrict__ out) {
    __shared__ float Es[SEQ];
    const int h   = blockIdx.x;
    const int tid = threadIdx.x;
    const float offh = off[h];
    const float* wh  = w + h * SEQ;
    for (int i = tid; i < SEQ; i += 256) Es[i] = __expf(wh[i] - offh);
    __syncthreads();
    const int n = blockIdx.y * 256 + tid;
    if (n < SEQ) {
        float s = 0.f;
        for (int t = 0; t < SEQ; ++t) {
            int k = n - t; k = (k < 0) ? -k : k;
            s += Es[k];
        }
        out[(size_t)BATCH * MAXPOS * NH * HD + (size_t)(n + 1) * NH + h] = s;
    }
}

// ---------------------------------------------------------------------------
// Zero the padded boundary positions (p=0, p=2047) of both outputs.
// d_out is poisoned 0xAA before every launch, so these must be written.
// ---------------------------------------------------------------------------
__global__ __launch_bounds__(256)
void zero_bounds_kernel(float* __restrict__ out) {
    const int i = blockIdx.x * 256 + threadIdx.x;
    const int plane = NH * HD;                 // 768
    if (i < 2 * BATCH * plane) {               // 12288 pbv boundary elems
        int side = i / (BATCH * plane);
        int r    = i % (BATCH * plane);
        int b    = r / plane;
        int j    = r % plane;
        int p    = side ? (MAXPOS - 1) : 0;
        out[((size_t)b * MAXPOS + p) * plane + j] = 0.f;
    }
    if (i < 2 * NH) {                          // 24 z_pb boundary elems
        size_t zb = (size_t)BATCH * MAXPOS * plane;
        int p = (i < NH) ? 0 : (MAXPOS - 1);
        out[zb + (size_t)p * NH + (i % NH)] = 0.f;
    }
}

extern "C" void kernel_launch(void* const* d_in, const int* in_sizes, int n_in,
                              void* d_out, int out_size, void* d_ws, size_t ws_size,
                              hipStream_t stream) {
    const float* v   = (const float*)d_in[0];  // (8, 2048, 12, 64)
    const float* off = (const float*)d_in[1];  // (1, 12)
    const float* w   = (const float*)d_in[2];  // (1, 12, 2046)
    float* out = (float*)d_out;                // pbv flat, then z_pb flat

    zero_bounds_kernel<<<48, 256, 0, stream>>>(out);
    zpb_kernel<<<dim3(NH, 8), 256, 0, stream>>>(w, off, out);
    pbv_kernel<<<dim3((SEQ + TN - 1) / TN, NH, BATCH), 256, 0, stream>>>(v, w, off, out);
}

// Round 2
// 211.421 us; speedup vs baseline: 4.9466x; 4.9466x over previous
//
#include <hip/hip_runtime.h>
#include <hip/hip_bf16.h>

#define BATCH 8
#define MAXPOS 2048
#define SEQ 2046
#define NH 12
#define HD 64
#define RLEN 4096
#define CENTER 2047
#define NCSLOT 254      // ci = c/16 in [-127,126], cslot = ci+127
#define TSTEPS 64       // K-chunks of 32 covering t=0..2047 (V zero-padded past 2045)
#define PLANE (NH * HD) // 768

typedef __attribute__((ext_vector_type(4))) float floatx4;
typedef __attribute__((ext_vector_type(8))) short shortx8;

// ws layout: [Atile: 12*254*512 bf16 = 3,121,152 B][Vbf: 8*12*64*4*64*8 bf16 = 25,165,824 B]
#define ATILE_BYTES (NH * NCSLOT * 512 * 2)

#define GLOAD_LDS16(src, dst)                                                  \
    __builtin_amdgcn_global_load_lds(                                          \
        (const __attribute__((address_space(1))) void*)(src),                  \
        (__attribute__((address_space(3))) void*)(dst), 16, 0, 0)

// ---------------------------------------------------------------------------
// prep_A: Toeplitz A-fragments in MFMA A-operand order, bf16.
// Tile (h, cslot): elem[lane][j] = R_h[CENTER + 16*ci + (lane>>4)*8 - (lane&15) + j]
// where R_h[x] = exp(w[h,|x-2047|] - off[h]) for |x-2047| < SEQ else 0.
// ---------------------------------------------------------------------------
__global__ __launch_bounds__(256)
void prep_A(const float* __restrict__ w, const float* __restrict__ off,
            ushort* __restrict__ atile) {
    __shared__ float R[RLEN];
    const int cslot = blockIdx.x;
    const int h     = blockIdx.y;
    const int tid   = threadIdx.x;
    const float offh = off[h];
    const float* wh  = w + h * SEQ;
    for (int x = tid; x < RLEN; x += 256) {
        int k = x - CENTER; k = (k < 0) ? -k : k;
        R[x] = (k < SEQ) ? __expf(wh[k] - offh) : 0.f;
    }
    __syncthreads();
    const int ci   = cslot - 127;
    const int lane = tid >> 2;
    const int jp   = (tid & 3) * 2;
    const int q    = lane >> 4;
    const int m    = lane & 15;
    const int es0  = CENTER + 16 * ci + q * 8 - m + jp;  // in [0, 4094-1]
    __hip_bfloat16 b0 = __float2bfloat16(R[es0]);
    __hip_bfloat16 b1 = __float2bfloat16(R[es0 + 1]);
    ushort2 pk;
    pk.x = *(ushort*)&b0;
    pk.y = *(ushort*)&b1;
    *(ushort2*)(atile + ((size_t)(h * NCSLOT + cslot) * 512 + lane * 8 + jp)) = pk;
}

// ---------------------------------------------------------------------------
// prep_V: V in MFMA B-operand fragment order, bf16, zero-padded for t>=SEQ.
// Frag block (b,h,tc,dt): elem[lane][j] = v[b, 1 + tc*32 + (lane>>4)*8 + j, h, dt*16 + (lane&15)]
// ---------------------------------------------------------------------------
__global__ __launch_bounds__(256)
void prep_V(const float* __restrict__ v, ushort* __restrict__ vbf) {
    const int slot = blockIdx.x * 256 + threadIdx.x;  // 1,572,864 slots
    int rem = slot;
    const int lane = rem & 63;  rem >>= 6;
    const int dt   = rem & 3;   rem >>= 2;
    const int tc   = rem & 63;  rem >>= 6;
    const int h    = rem % NH;
    const int b    = rem / NH;
    const int q    = lane >> 4;
    const int dcol = lane & 15;
    const int d    = dt * 16 + dcol;
    const int tb   = tc * 32 + q * 8;
    ushort pk[8];
#pragma unroll
    for (int j = 0; j < 8; ++j) {
        int t = tb + j;
        float val = (t < SEQ) ? v[((size_t)(b * MAXPOS + 1 + t) * NH + h) * HD + d] : 0.f;
        __hip_bfloat16 bv = __float2bfloat16(val);
        pk[j] = *(ushort*)&bv;
    }
    *(uint4*)(vbf + (size_t)slot * 8) = *(uint4*)pk;
}

// ---------------------------------------------------------------------------
// gemm_pbv: block = 4 waves; wave w handles batch b = bgrp*4+w, 128n x 64d.
// Block covers n-tile of 128 (8 subtiles of 16) for one (h, bgrp).
// A-frags (shared across waves) + per-wave B-frags staged via global_load_lds.
// ---------------------------------------------------------------------------
__global__ __launch_bounds__(256, 2)
void gemm_pbv(const ushort* __restrict__ atile, const ushort* __restrict__ vbf,
              float* __restrict__ out) {
    __shared__ short As[8 * 512];       // 8 KB
    __shared__ short Bs[4 * 4 * 512];   // 16 KB

    const int ntile = blockIdx.x;       // 0..15, n0 = ntile*128
    const int bgrp  = blockIdx.y;       // 0..1
    const int h     = blockIdx.z;       // 0..11
    const int tid   = threadIdx.x;
    const int w     = tid >> 6;
    const int lane  = tid & 63;
    const int bb    = bgrp * 4 + w;
    const int n0    = ntile * 128;

    floatx4 acc[8][4];
#pragma unroll
    for (int s = 0; s < 8; ++s)
#pragma unroll
        for (int dt = 0; dt < 4; ++dt) acc[s][dt] = (floatx4){0.f, 0.f, 0.f, 0.f};

    const ushort* abase = atile + (size_t)h * NCSLOT * 512 + lane * 8;
    const ushort* vbase = vbf + ((size_t)(bb * NH + h) * TSTEPS * 4 + 0) * 512 + lane * 8;

    for (int tc = 0; tc < TSTEPS; ++tc) {
        __syncthreads();  // previous iteration's LDS reads complete
        // stage A: wave w loads subtiles s = 2w, 2w+1
#pragma unroll
        for (int i = 0; i < 2; ++i) {
            int s = 2 * w + i;
            int cslot = tc * 2 - ntile * 8 - s + 127;  // in [0, 253]
            GLOAD_LDS16(abase + (size_t)cslot * 512, &As[s * 512]);
        }
        // stage B: wave w loads its batch's 4 d-tiles for this k-chunk
#pragma unroll
        for (int dt = 0; dt < 4; ++dt) {
            GLOAD_LDS16(vbase + ((size_t)tc * 4 + dt) * 512, &Bs[(w * 4 + dt) * 512]);
        }
        __syncthreads();  // staging visible (vmcnt drained by barrier)

        shortx8 af[8], bf[4];
#pragma unroll
        for (int s = 0; s < 8; ++s) af[s] = *(const shortx8*)&As[s * 512 + lane * 8];
#pragma unroll
        for (int dt = 0; dt < 4; ++dt) bf[dt] = *(const shortx8*)&Bs[(w * 4 + dt) * 512 + lane * 8];
#pragma unroll
        for (int s = 0; s < 8; ++s)
#pragma unroll
            for (int dt = 0; dt < 4; ++dt)
                acc[s][dt] = __builtin_amdgcn_mfma_f32_16x16x32_bf16(af[s], bf[dt], acc[s][dt], 0, 0, 0);
    }

    // epilogue: D row = (lane>>4)*4 + r (n-local), col = lane&15 (d-local)
    const int q    = lane >> 4;
    const int dcol = lane & 15;
#pragma unroll
    for (int s = 0; s < 8; ++s) {
        int nsb = n0 + s * 16 + q * 4;
#pragma unroll
        for (int r = 0; r < 4; ++r) {
            int n = nsb + r;
            if (n < SEQ) {
                float* ob = out + ((size_t)(bb * MAXPOS + 1 + n) * NH + h) * HD + dcol;
#pragma unroll
                for (int dt = 0; dt < 4; ++dt) ob[dt * 16] = acc[s][dt][r];
            }
        }
    }
}

// ---------------------------------------------------------------------------
// z_pb[1+n, h] = sum_t exp(w[h,|n-t|]-off[h])  (tiny; fp32)
// ---------------------------------------------------------------------------
__global__ __launch_bounds__(256)
void zpb_kernel(const float* __restrict__ w, const float* __restrict__ off,
                float* __restrict__ out) {
    __shared__ float Es[SEQ];
    const int h   = blockIdx.x;
    const int tid = threadIdx.x;
    const float offh = off[h];
    const float* wh  = w + h * SEQ;
    for (int i = tid; i < SEQ; i += 256) Es[i] = __expf(wh[i] - offh);
    __syncthreads();
    const int n = blockIdx.y * 256 + tid;
    if (n < SEQ) {
        float s = 0.f;
        for (int t = 0; t < SEQ; ++t) {
            int k = n - t; k = (k < 0) ? -k : k;
            s += Es[k];
        }
        out[(size_t)BATCH * MAXPOS * PLANE + (size_t)(n + 1) * NH + h] = s;
    }
}

// ---------------------------------------------------------------------------
// Zero the padded boundary positions (p=0, p=2047) of both outputs.
// ---------------------------------------------------------------------------
__global__ __launch_bounds__(256)
void zero_bounds_kernel(float* __restrict__ out) {
    const int i = blockIdx.x * 256 + threadIdx.x;
    if (i < 2 * BATCH * PLANE) {
        int side = i / (BATCH * PLANE);
        int r    = i % (BATCH * PLANE);
        int b    = r / PLANE;
        int j    = r % PLANE;
        int p    = side ? (MAXPOS - 1) : 0;
        out[((size_t)b * MAXPOS + p) * PLANE + j] = 0.f;
    }
    if (i < 2 * NH) {
        size_t zb = (size_t)BATCH * MAXPOS * PLANE;
        int p = (i < NH) ? 0 : (MAXPOS - 1);
        out[zb + (size_t)p * NH + (i % NH)] = 0.f;
    }
}

extern "C" void kernel_launch(void* const* d_in, const int* in_sizes, int n_in,
                              void* d_out, int out_size, void* d_ws, size_t ws_size,
                              hipStream_t stream) {
    const float* v   = (const float*)d_in[0];  // (8, 2048, 12, 64)
    const float* off = (const float*)d_in[1];  // (1, 12)
    const float* w   = (const float*)d_in[2];  // (1, 12, 2046)
    float* out = (float*)d_out;

    ushort* atile = (ushort*)d_ws;
    ushort* vbf   = (ushort*)((char*)d_ws + ATILE_BYTES);

    zero_bounds_kernel<<<48, 256, 0, stream>>>(out);
    zpb_kernel<<<dim3(NH, 8), 256, 0, stream>>>(w, off, out);
    prep_A<<<dim3(NCSLOT, NH), 256, 0, stream>>>(w, off, atile);
    prep_V<<<6144, 256, 0, stream>>>(v, vbf);
    gemm_pbv<<<dim3(16, 2, NH), 256, 0, stream>>>(atile, vbf, out);
}

// Round 3
// 155.342 us; speedup vs baseline: 6.7324x; 1.3610x over previous
//
#include <hip/hip_runtime.h>
#include <hip/hip_bf16.h>

#define BATCH 8
#define MAXPOS 2048
#define SEQ 2046
#define NH 12
#define HD 64
#define CENTER 2047
#define NCSLOT 254      // ci = c/16 in [-127,126], cslot = ci+127
#define TSTEPS 64       // K-chunks of 32 covering t=0..2047 (zero-padded past 2045)
#define PLANE (NH * HD) // 768

typedef __attribute__((ext_vector_type(4))) float floatx4;
typedef __attribute__((ext_vector_type(8))) short shortx8;

// ws layout: [Atile: 12*254*512 bf16 = 3,121,152 B][Vbf: 8*12*256*512 bf16 = 25,165,824 B]
#define ATILE_BYTES (NH * NCSLOT * 512 * 2)

// ---------------------------------------------------------------------------
// prep_A: Toeplitz A-fragments in MFMA A-operand order, bf16. Each thread
// computes exactly the 2 exp values it stores (no redundant table build).
// Tile (h,cslot) elem[lane][j] = exp(w[h,|16*ci + (lane>>4)*8 - (lane&15) + j|] - off)
// ---------------------------------------------------------------------------
__global__ __launch_bounds__(256)
void prep_A(const float* __restrict__ w, const float* __restrict__ off,
            ushort* __restrict__ atile) {
    const int cslot = blockIdx.x;
    const int h     = blockIdx.y;
    const int tid   = threadIdx.x;
    const float offh = off[h];
    const float* wh  = w + h * SEQ;
    const int ci   = cslot - 127;
    const int lane = tid >> 2;
    const int jp   = (tid & 3) * 2;
    const int q    = lane >> 4;
    const int m    = lane & 15;
    const int d0   = 16 * ci + q * 8 - m + jp;   // signed lag
    ushort pk[2];
#pragma unroll
    for (int e = 0; e < 2; ++e) {
        int k = d0 + e; k = (k < 0) ? -k : k;
        float val = (k < SEQ) ? __expf(wh[k] - offh) : 0.f;
        __hip_bfloat16 bv = __float2bfloat16(val);
        pk[e] = *(ushort*)&bv;
    }
    *(ushort2*)(atile + ((size_t)(h * NCSLOT + cslot) * 512 + lane * 8 + jp)) = *(ushort2*)pk;
}

// ---------------------------------------------------------------------------
// prep_V: LDS transpose. Block = (tc, h, b): coalesced float4 reads of 32
// t-rows x 64 d, then each wave emits one dt fragment set, coalesced uint4 writes.
// ---------------------------------------------------------------------------
__global__ __launch_bounds__(256)
void prep_V(const float* __restrict__ v, ushort* __restrict__ vbf) {
    __shared__ float Ls[32][64];
    const int tc  = blockIdx.x;
    const int h   = blockIdx.y;
    const int b   = blockIdx.z;
    const int tid = threadIdx.x;
#pragma unroll
    for (int i = 0; i < 2; ++i) {
        int idx = tid + 256 * i;          // 0..511
        int row = idx >> 4;
        int c4  = (idx & 15) * 4;
        int t   = tc * 32 + row;
        float4 val = make_float4(0.f, 0.f, 0.f, 0.f);
        if (t < SEQ) val = *(const float4*)(v + ((size_t)(b * MAXPOS + 1 + t) * NH + h) * HD + c4);
        *(float4*)&Ls[row][c4] = val;
    }
    __syncthreads();
    const int wv   = tid >> 6;            // dt
    const int lane = tid & 63;
    const int q    = lane >> 4;
    const int dcol = lane & 15;
    ushort pk[8];
#pragma unroll
    for (int j = 0; j < 8; ++j) {
        __hip_bfloat16 bv = __float2bfloat16(Ls[q * 8 + j][wv * 16 + dcol]);
        pk[j] = *(ushort*)&bv;
    }
    *(uint4*)(vbf + ((size_t)((b * NH + h) * TSTEPS + tc) * 4 + wv) * 512 + lane * 8) = *(uint4*)pk;
}

// ---------------------------------------------------------------------------
// gemm_pbv: barrier-free, LDS-free, register double-buffered MFMA pipeline.
// Block = (nt, h, bpair), 4 waves: wave (sh = w>>1) handles n-half, (w&1) batch.
// A shared 2x and B shared 2x across waves via L1. XCD swizzle: all 16 nt of a
// (h,bpair) group land on one XCD so Vbf/Atile are L2-resident.
// ---------------------------------------------------------------------------
#define LOADA(dst, tc_)                                                        \
    _Pragma("unroll") for (int s = 0; s < 4; ++s)                              \
        dst[s] = *(const shortx8*)(aP + ((tc_) * 2 - s) * 512);
#define LOADB(dst, tc_)                                                        \
    _Pragma("unroll") for (int dt = 0; dt < 4; ++dt)                           \
        dst[dt] = *(const shortx8*)(bP + ((tc_) * 4 + dt) * 512);

__global__ __launch_bounds__(256, 3)
void gemm_pbv(const ushort* __restrict__ atile, const ushort* __restrict__ vbf,
              float* __restrict__ out) {
    const int bid  = blockIdx.x;          // 0..767
    const int slot = bid >> 3;            // 0..95
    const int g    = (bid & 7) * 6 + (slot % 6);  // group 0..47 -> (h,bpair)
    const int nt   = slot / 6;            // 0..15
    const int h    = g >> 2;
    const int bpair= g & 3;
    const int tid  = threadIdx.x;
    const int wv   = tid >> 6;
    const int lane = tid & 63;
    const int bb   = bpair * 2 + (wv & 1);
    const int sh   = wv >> 1;
    const int sbase= nt * 8 + sh * 4;     // absolute 16-row subtile index base

    floatx4 acc[4][4];
#pragma unroll
    for (int s = 0; s < 4; ++s)
#pragma unroll
        for (int dt = 0; dt < 4; ++dt) acc[s][dt] = (floatx4){0.f, 0.f, 0.f, 0.f};

    // cslot(tc,s) = 2*tc - (sbase+s) + 127  (in [0,253])
    const ushort* aP = atile + ((size_t)h * NCSLOT + (127 - sbase)) * 512 + lane * 8;
    const ushort* bP = vbf + (size_t)(bb * NH + h) * TSTEPS * 4 * 512 + lane * 8;

    shortx8 a0[4], b0[4], a1[4], b1[4];
    LOADA(a0, 0); LOADB(b0, 0);
    for (int tc = 0; tc < TSTEPS; tc += 2) {
        LOADA(a1, tc + 1); LOADB(b1, tc + 1);
#pragma unroll
        for (int s = 0; s < 4; ++s)
#pragma unroll
            for (int dt = 0; dt < 4; ++dt)
                acc[s][dt] = __builtin_amdgcn_mfma_f32_16x16x32_bf16(a0[s], b0[dt], acc[s][dt], 0, 0, 0);
        if (tc + 2 < TSTEPS) { LOADA(a0, tc + 2); LOADB(b0, tc + 2); }
#pragma unroll
        for (int s = 0; s < 4; ++s)
#pragma unroll
            for (int dt = 0; dt < 4; ++dt)
                acc[s][dt] = __builtin_amdgcn_mfma_f32_16x16x32_bf16(a1[s], b1[dt], acc[s][dt], 0, 0, 0);
    }

    // epilogue: D row=(lane>>4)*4+r (n-local), col=lane&15 (d-local)
    const int q    = lane >> 4;
    const int dcol = lane & 15;
    const int n0   = nt * 128 + sh * 64;
#pragma unroll
    for (int s = 0; s < 4; ++s) {
        int nsb = n0 + s * 16 + q * 4;
#pragma unroll
        for (int r = 0; r < 4; ++r) {
            int n = nsb + r;
            if (n < SEQ) {
                float* ob = out + ((size_t)(bb * MAXPOS + 1 + n) * NH + h) * HD + dcol;
#pragma unroll
                for (int dt = 0; dt < 4; ++dt) ob[dt * 16] = acc[s][dt][r];
            }
        }
    }
}

// ---------------------------------------------------------------------------
// zpb: z_pb[1+n,h] = S(n) + S(SEQ-1-n) - E[0], S = inclusive prefix of E.
// One block per head; block-wide scan (thread-local 8 + wave shfl scan).
// ---------------------------------------------------------------------------
__global__ __launch_bounds__(256)
void zpb_kernel(const float* __restrict__ w, const float* __restrict__ off,
                float* __restrict__ out) {
    __shared__ float Es[SEQ];
    __shared__ float Ss[SEQ];
    __shared__ float wsum[4];
    const int h   = blockIdx.x;
    const int tid = threadIdx.x;
    const int wid = tid >> 6;
    const int lane = tid & 63;
    const float offh = off[h];
    const float* wh  = w + h * SEQ;
    for (int i = tid; i < SEQ; i += 256) Es[i] = __expf(wh[i] - offh);
    __syncthreads();
    const int base = tid * 8;
    float loc[8];
    float s = 0.f;
#pragma unroll
    for (int j = 0; j < 8; ++j) {
        float e = (base + j < SEQ) ? Es[base + j] : 0.f;
        s += e; loc[j] = s;
    }
    float sc = s;
#pragma unroll
    for (int d = 1; d < 64; d <<= 1) {
        float t = __shfl_up(sc, d);
        if (lane >= d) sc += t;
    }
    if (lane == 63) wsum[wid] = sc;
    __syncthreads();
    float woff = 0.f;
    for (int k = 0; k < wid; ++k) woff += wsum[k];
    float prefix = woff + sc - s;     // exclusive prefix of this thread's chunk
#pragma unroll
    for (int j = 0; j < 8; ++j)
        if (base + j < SEQ) Ss[base + j] = prefix + loc[j];
    __syncthreads();
    const float E0 = Es[0];
    const size_t zb = (size_t)BATCH * MAXPOS * PLANE;
    for (int i = tid; i < SEQ; i += 256)
        out[zb + (size_t)(i + 1) * NH + h] = Ss[i] + Ss[SEQ - 1 - i] - E0;
}

// ---------------------------------------------------------------------------
// Zero the padded boundary positions (p=0, p=2047) of both outputs.
// ---------------------------------------------------------------------------
__global__ __launch_bounds__(256)
void zero_bounds_kernel(float* __restrict__ out) {
    const int i = blockIdx.x * 256 + threadIdx.x;
    if (i < 2 * BATCH * PLANE) {
        int side = i / (BATCH * PLANE);
        int r    = i % (BATCH * PLANE);
        int b    = r / PLANE;
        int j    = r % PLANE;
        int p    = side ? (MAXPOS - 1) : 0;
        out[((size_t)b * MAXPOS + p) * PLANE + j] = 0.f;
    }
    if (i < 2 * NH) {
        size_t zb = (size_t)BATCH * MAXPOS * PLANE;
        int p = (i < NH) ? 0 : (MAXPOS - 1);
        out[zb + (size_t)p * NH + (i % NH)] = 0.f;
    }
}

extern "C" void kernel_launch(void* const* d_in, const int* in_sizes, int n_in,
                              void* d_out, int out_size, void* d_ws, size_t ws_size,
                              hipStream_t stream) {
    const float* v   = (const float*)d_in[0];  // (8, 2048, 12, 64)
    const float* off = (const float*)d_in[1];  // (1, 12)
    const float* w   = (const float*)d_in[2];  // (1, 12, 2046)
    float* out = (float*)d_out;

    ushort* atile = (ushort*)d_ws;
    ushort* vbf   = (ushort*)((char*)d_ws + ATILE_BYTES);

    zero_bounds_kernel<<<48, 256, 0, stream>>>(out);
    zpb_kernel<<<NH, 256, 0, stream>>>(w, off, out);
    prep_A<<<dim3(NCSLOT, NH), 256, 0, stream>>>(w, off, atile);
    prep_V<<<dim3(TSTEPS, NH, BATCH), 256, 0, stream>>>(v, vbf);
    gemm_pbv<<<768, 256, 0, stream>>>(atile, vbf, out);
}